// Round 18
// baseline (462.518 us; speedup 1.0000x reference)
//
#include <hip/hip_runtime.h>

#define T_STEPS 60
#define HID 128
#define ROWS 16
#define NBLK (16384 / ROWS)  // 1024 blocks x 1024 threads

typedef __attribute__((ext_vector_type(8))) short short8;
typedef __attribute__((ext_vector_type(4))) float f32x4;

#define K1 1.44269504088896340736f  // log2(e)

__device__ __forceinline__ unsigned short f2bf(float f) {
  unsigned u = __float_as_uint(f);
  return (unsigned short)((u + 0x7fffu + ((u >> 16) & 1u)) >> 16);
}
__device__ __forceinline__ float sigm(float x) {
  return __builtin_amdgcn_rcpf(1.0f + __expf(-x));
}
// butterfly-add over the 16-lane DPP row
template <int CTRL>
__device__ __forceinline__ float dppadd(float x) {
  int y = __builtin_amdgcn_update_dpp(0, __builtin_bit_cast(int, x), CTRL, 0xf,
                                      0xf, false);
  return x + __builtin_bit_cast(float, y);
}

// LDS map (bytes):
//   [0,8192):        h dbuf (2 x 4096): [row][unit] bf16, row r at r*256,
//                    XOR-swizzled bits 4-6
//   [8192,74240):    preact partials: half h at PRE+h*33024;
//                    [row r at r*2064][unit u at u*16] = f32x4 {i,f,g,o}
//                    (stride 2064 = 516 dwords: l4-groups land >=2-way max)
//   [74240,107008):  xp f32 acc-layout: gt*8192 + (ug*64+lane)*16
//   [107008,110848): out staging [16 rows][60 t] f32
#define HB 0
#define PRE 8192
#define PRE_H 33024
#define PRE_R 2064
#define XP 74240
#define OS 107008
#define LDS_BYTES 110848

// K-split decomposition: wave pair (ug) = same 16 units x 4 gates; half=0
// does kt{0,1}+xp-Cinit, half=1 does kt{2,3}+C=0. bw = 32 regs/wave ->
// demand ~100 < 128-reg cap at 4 waves/SIMD: spill-free AND 4 chains/SIMD
// (R7-R17 plateau: spill<->TLP tradeoff; this gets both).
__global__ __launch_bounds__(1024, 4) void lstm_fused(
    const float* __restrict__ x, const float* __restrict__ W_enc,
    const float* __restrict__ b_enc, const float* __restrict__ W_ih,
    const float* __restrict__ W_hh, const float* __restrict__ b_ih,
    const float* __restrict__ b_hh, const float* __restrict__ W_dec,
    const float* __restrict__ b_dec, float* __restrict__ out) {
  __shared__ __align__(16) unsigned char lds[LDS_BYTES];

  const int tid = threadIdx.x;
  const int wav = tid >> 6;   // 0..15
  const int lane = tid & 63;
  const int l15 = lane & 15;
  const int l4 = lane >> 4;
  const int ug = wav >> 1;    // unit-group: units ug*16..ug*16+15
  const int half = wav & 1;   // kt pair: {0,1} or {2,3}
  const int u = ug * 16 + l15;
  const int row0 = blockIdx.x * ROWS;

  // zero h buf0 (4096 B)
  if (tid < 1024) ((unsigned*)(lds + HB))[tid] = 0u;

  // ---- xp = enc @ W_ih^T + b_ih + b_hh (f32, exact); half=0 stores ----
  {
    f32x4 xp4[4];
    float xr0[4], xr1[4], xr2[4];
#pragma unroll
    for (int v = 0; v < 4; ++v) {
      int r = 4 * l4 + v;
      const float* xp_ = x + (size_t)(row0 + r) * 3;
      xr0[v] = xp_[0];
      xr1[v] = xp_[1];
      xr2[v] = xp_[2];
    }
#pragma unroll
    for (int gt = 0; gt < 4; ++gt) {
      float bias = b_ih[gt * 128 + u] + b_hh[gt * 128 + u];
#pragma unroll
      for (int v = 0; v < 4; ++v) xp4[gt][v] = bias;
    }
    const f32x4* wp0 = (const f32x4*)(W_ih + (size_t)u * 64);
    const f32x4* wp1 = (const f32x4*)(W_ih + (size_t)(128 + u) * 64);
    const f32x4* wp2 = (const f32x4*)(W_ih + (size_t)(256 + u) * 64);
    const f32x4* wp3 = (const f32x4*)(W_ih + (size_t)(384 + u) * 64);
    for (int e4 = 0; e4 < 16; ++e4) {
      f32x4 w0 = wp0[e4], w1 = wp1[e4], w2 = wp2[e4], w3 = wp3[e4];
#pragma unroll
      for (int jj = 0; jj < 4; ++jj) {
        int e = e4 * 4 + jj;
        float we0 = W_enc[e * 3], we1 = W_enc[e * 3 + 1], we2 = W_enc[e * 3 + 2];
        float be = b_enc[e];
#pragma unroll
        for (int v = 0; v < 4; ++v) {
          float ev = fmaf(we0, xr0[v], fmaf(we1, xr1[v], fmaf(we2, xr2[v], be)));
          xp4[0][v] = fmaf(w0[jj], ev, xp4[0][v]);
          xp4[1][v] = fmaf(w1[jj], ev, xp4[1][v]);
          xp4[2][v] = fmaf(w2[jj], ev, xp4[2][v]);
          xp4[3][v] = fmaf(w3[jj], ev, xp4[3][v]);
        }
      }
    }
    if (half == 0) {
#pragma unroll
      for (int gt = 0; gt < 4; ++gt) {
        float s = (gt == 2) ? (-2.0f * K1) : (-K1);
#pragma unroll
        for (int v = 0; v < 4; ++v) xp4[gt][v] *= s;
        *(f32x4*)(lds + XP + (unsigned)gt * 8192 +
                  (unsigned)(ug * 64 + lane) * 16) = xp4[gt];
      }
    }
  }

  // ---- W_hh bf16 B-frags for this wave's kt pair, exp2-prescaled ----
  short8 bw[4][2];
#pragma unroll
  for (int gt = 0; gt < 4; ++gt) {
    float s = (gt == 2) ? (-2.0f * K1) : (-K1);
#pragma unroll
    for (int j = 0; j < 2; ++j) {
      int kt = 2 * half + j;
      const float* p = W_hh + (size_t)(gt * 128 + u) * HID + kt * 32 + 8 * l4;
      short8 f;
#pragma unroll
      for (int jj = 0; jj < 8; ++jj) f[jj] = (short)f2bf(s * p[jj]);
      bw[gt][j] = f;
    }
  }

  // c-state (scaled domain) for P2's 2 (row=wav, unit) slots
  float ct0 = 0.0f, ct1 = 0.0f;

  // ---- addresses ----
  // P1 A-frag reads: kt = 2*half+j -> byte off (l4*16 + half*128 [+64]) ^ swz
  // (l4*16<=48, +64 -> <=112 < 128: no carry into bit7; R16 lesson respected)
  const unsigned swzA =
      (((unsigned)(l15 & 7)) << 4) ^ (((unsigned)(l15 & 8)) << 2);
  const unsigned rdA =
      ((unsigned)(l15 * 256 + l4 * 16 + half * 128)) ^ swzA;
  const unsigned rdB =
      ((unsigned)(l15 * 256 + l4 * 16 + half * 128 + 64)) ^ swzA;
  // P1 preact write base (v strides PRE_R)
  const unsigned pwr = PRE + (unsigned)half * PRE_H +
                       (unsigned)(4 * l4) * PRE_R + (unsigned)(ug * 16 + l15) * 16;
  const unsigned xpAddr = XP + (unsigned)(ug * 64 + lane) * 16;
  // P2: row rw = wav; units u0 = lane, u1 = lane+64
  const int rw = wav;
  const unsigned prd0 = PRE + (unsigned)rw * PRE_R + (unsigned)lane * 16;
  const unsigned prd1 = prd0 + 1024;  // +64 units * 16B
  const unsigned swzR =
      (((unsigned)(rw & 7)) << 4) ^ (((unsigned)(rw & 8)) << 2);
  const unsigned hw0 = ((unsigned)(rw * 256 + 2 * lane)) ^ swzR;
  const unsigned hw1 = ((unsigned)(rw * 256 + 2 * lane + 128)) ^ swzR;
  const float wd0 = W_dec[lane];
  const float wd1 = W_dec[lane + 64];
  const unsigned osA = OS + (unsigned)(rw * T_STEPS) * 4;
  const float kneg = -2.0f * K1;
  const float kpos = 2.0f * K1;

  unsigned hbR = HB, hbW = HB + 4096;

  __syncthreads();

  // gate math in exp2 domain (R7-verified):
  //   e^{-i}=2^s0, e^{-f}=2^s1, e^{-2g}=2^s2, e^{-o}=2^s3
  //   ct' = [ct*A*G + k(1-eg)*F]/(F*A*G), k=-2log2e;  h=(1-ec)/(Bo*(1+ec))
#define ACT(S, CT, H)                                                          \
  {                                                                            \
    float ea = __builtin_amdgcn_exp2f(S[0]);                                   \
    float ef = __builtin_amdgcn_exp2f(S[1]);                                   \
    float eg = __builtin_amdgcn_exp2f(S[2]);                                   \
    float eo = __builtin_amdgcn_exp2f(S[3]);                                   \
    float A = 1.0f + ea, F = 1.0f + ef, G = 1.0f + eg, Bo = 1.0f + eo;         \
    float AG = A * G;                                                          \
    float r = __builtin_amdgcn_rcpf(F * AG);                                   \
    float tt = fmaf(kpos, eg, kneg);                                           \
    float num = fmaf(CT, AG, tt * F);                                          \
    float cn = num * r;                                                        \
    CT = cn;                                                                   \
    float ec = __builtin_amdgcn_exp2f(cn);                                     \
    float r2 = __builtin_amdgcn_rcpf(Bo * (1.0f + ec));                        \
    H = (1.0f - ec) * r2;                                                      \
  }

#pragma clang loop unroll(disable)
  for (int t = 0; t < T_STEPS; ++t) {
    // ---- P1: partial gates = (xp|0) + h @ W_hh[kt-half]^T ----
    short8 afa = *(const short8*)(lds + hbR + rdA);
    short8 afb = *(const short8*)(lds + hbR + rdB);
    f32x4 a0, a1, a2, a3;
    if (half == 0) {
      a0 = __builtin_amdgcn_mfma_f32_16x16x32_bf16(
          afa, bw[0][0], *(const f32x4*)(lds + xpAddr), 0, 0, 0);
      a1 = __builtin_amdgcn_mfma_f32_16x16x32_bf16(
          afa, bw[1][0], *(const f32x4*)(lds + xpAddr + 8192), 0, 0, 0);
      a2 = __builtin_amdgcn_mfma_f32_16x16x32_bf16(
          afa, bw[2][0], *(const f32x4*)(lds + xpAddr + 16384), 0, 0, 0);
      a3 = __builtin_amdgcn_mfma_f32_16x16x32_bf16(
          afa, bw[3][0], *(const f32x4*)(lds + xpAddr + 24576), 0, 0, 0);
    } else {
      f32x4 z = {};
      a0 = __builtin_amdgcn_mfma_f32_16x16x32_bf16(afa, bw[0][0], z, 0, 0, 0);
      a1 = __builtin_amdgcn_mfma_f32_16x16x32_bf16(afa, bw[1][0], z, 0, 0, 0);
      a2 = __builtin_amdgcn_mfma_f32_16x16x32_bf16(afa, bw[2][0], z, 0, 0, 0);
      a3 = __builtin_amdgcn_mfma_f32_16x16x32_bf16(afa, bw[3][0], z, 0, 0, 0);
    }
    a0 = __builtin_amdgcn_mfma_f32_16x16x32_bf16(afb, bw[0][1], a0, 0, 0, 0);
    a1 = __builtin_amdgcn_mfma_f32_16x16x32_bf16(afb, bw[1][1], a1, 0, 0, 0);
    a2 = __builtin_amdgcn_mfma_f32_16x16x32_bf16(afb, bw[2][1], a2, 0, 0, 0);
    a3 = __builtin_amdgcn_mfma_f32_16x16x32_bf16(afb, bw[3][1], a3, 0, 0, 0);
    // transpose-pack per row v: {i,f,g,o} -> PRE[row][unit]
#pragma unroll
    for (int v = 0; v < 4; ++v) {
      f32x4 q;
      q[0] = a0[v]; q[1] = a1[v]; q[2] = a2[v]; q[3] = a3[v];
      *(f32x4*)(lds + pwr + (unsigned)v * PRE_R) = q;
    }
    __syncthreads();

    // ---- P2: row rw, units {lane, lane+64}: combine halves + activate ----
    f32x4 sa = *(const f32x4*)(lds + prd0);
    {
      f32x4 t2 = *(const f32x4*)(lds + prd0 + PRE_H);
      sa += t2;
    }
    f32x4 sb = *(const f32x4*)(lds + prd1);
    {
      f32x4 t2 = *(const f32x4*)(lds + prd1 + PRE_H);
      sb += t2;
    }
    float h0, h1;
    ACT(sa, ct0, h0)
    ACT(sb, ct1, h1)
    *(unsigned short*)(lds + hbW + hw0) = f2bf(h0);
    *(unsigned short*)(lds + hbW + hw1) = f2bf(h1);
    // decode: full-wave reduction, no LDS partials
    float pz = fmaf(h0, wd0, h1 * wd1);
    pz = dppadd<0x140>(dppadd<0x141>(dppadd<0x4E>(dppadd<0xB1>(pz))));
    pz += __shfl_xor(pz, 16, 64);
    pz += __shfl_xor(pz, 32, 64);
    if (lane == 0) *(float*)(lds + osA + (unsigned)t * 4) = pz;
    __syncthreads();
    unsigned tmp = hbR; hbR = hbW; hbW = tmp;
  }
#undef ACT

  // ---- epilogue: sigmoid + coalesced store ----
  const float bdec = b_dec[0];
  const float* OSf = (const float*)(lds + OS);
  if (tid < ROWS * T_STEPS)
    out[(size_t)row0 * T_STEPS + tid] = sigm(OSf[tid] + bdec);
}

extern "C" void kernel_launch(void* const* d_in, const int* in_sizes, int n_in,
                              void* d_out, int out_size, void* d_ws, size_t ws_size,
                              hipStream_t stream) {
  const float* x = (const float*)d_in[0];
  const float* W_enc = (const float*)d_in[1];
  const float* b_enc = (const float*)d_in[2];
  const float* W_ih = (const float*)d_in[3];
  const float* W_hh = (const float*)d_in[4];
  const float* b_ih = (const float*)d_in[5];
  const float* b_hh = (const float*)d_in[6];
  const float* W_dec = (const float*)d_in[7];
  const float* b_dec = (const float*)d_in[8];
  float* out = (float*)d_out;

  dim3 grid(NBLK);  // 1024 blocks x 16 rows
  dim3 block(1024);
  lstm_fused<<<grid, block, 0, stream>>>(x, W_enc, b_enc, W_ih, W_hh, b_ih, b_hh,
                                         W_dec, b_dec, out);
}

// Round 20
// 238.170 us; speedup vs baseline: 1.9420x; 1.9420x over previous
//
#include <hip/hip_runtime.h>

#define T_STEPS 60
#define HID 128
#define ROWS 16
#define NBLK (16384 / ROWS)  // 1024 blocks

typedef __attribute__((ext_vector_type(8))) short short8;
typedef __attribute__((ext_vector_type(4))) float f32x4;
typedef __attribute__((ext_vector_type(2))) float f32x2;

#define K1 1.44269504088896340736f  // log2(e)

__device__ __forceinline__ unsigned short f2bf(float f) {
  unsigned u = __float_as_uint(f);
  return (unsigned short)((u + 0x7fffu + ((u >> 16) & 1u)) >> 16);
}
__device__ __forceinline__ float sigm(float x) {
  return __builtin_amdgcn_rcpf(1.0f + __expf(-x));
}
// butterfly-add over the 16-lane DPP row (sums l15 dimension, preserves l4)
template <int CTRL>
__device__ __forceinline__ float dppadd(float x) {
  int y = __builtin_amdgcn_update_dpp(0, __builtin_bit_cast(int, x), CTRL, 0xf,
                                      0xf, false);
  return x + __builtin_bit_cast(float, y);
}
// packed f32 via PLAIN vector ops — compiler emits v_pk_*_f32 on gfx950 when
// profitable; elementwise IEEE semantics identical to scalar (R19's hand asm
// pk NaN'd; never hand-write what ISel does right).
__device__ __forceinline__ f32x2 vfma(f32x2 a, f32x2 b, f32x2 c) {
  return __builtin_elementwise_fma(a, b, c);
}

// LDS map (bytes): identical to R13/R14
//   [0,4096):      h buffer 0 (16 rows x 128 units bf16, row r at r*256, swizzled)
//   [4096,8192):   h buffer 1
//   [8192,40960):  xp f32 acc layout: gate gt at 8192+gt*8192+tid*16
//   [40960,71936): decode partials f32: [8 waves][60 t][16 rows], stride 968 f32
#define HB0 0
#define HB1 4096
#define XP_BASE 8192
#define PART 40960
#define WSTRIDE 968
#define LDS_BYTES (PART + 8 * WSTRIDE * 4)

__global__ __launch_bounds__(512, 4) void lstm_fused(
    const float* __restrict__ x, const float* __restrict__ W_enc,
    const float* __restrict__ b_enc, const float* __restrict__ W_ih,
    const float* __restrict__ W_hh, const float* __restrict__ b_ih,
    const float* __restrict__ b_hh, const float* __restrict__ W_dec,
    const float* __restrict__ b_dec, float* __restrict__ out) {
  __shared__ __align__(16) unsigned char lds[LDS_BYTES];

  const int tid = threadIdx.x;
  const int wav = tid >> 6;
  const int lane = tid & 63;
  const int l15 = lane & 15;
  const int l4 = lane >> 4;
  const int u = wav * 16 + l15;        // hidden unit owned by this lane
  const int row0 = blockIdx.x * ROWS;  // global batch row base

  // zero h buf0 (4096 B)
  for (int i = tid; i < 1024; i += 512) ((unsigned*)(lds + HB0))[i] = 0u;

  // ---- xp = enc @ W_ih^T + b_ih + b_hh -> LDS as f32 (exact), acc layout ----
  // (f16 xp was the R3/R5 failure: PRECISION, not location. f32 is exact.)
  {
    f32x4 xp4[4];
    float xr0[4], xr1[4], xr2[4];
#pragma unroll
    for (int v = 0; v < 4; ++v) {
      int r = 4 * l4 + v;
      const float* xp_ = x + (size_t)(row0 + r) * 3;
      xr0[v] = xp_[0];
      xr1[v] = xp_[1];
      xr2[v] = xp_[2];
    }
#pragma unroll
    for (int gt = 0; gt < 4; ++gt) {
      float bias = b_ih[gt * 128 + u] + b_hh[gt * 128 + u];
#pragma unroll
      for (int v = 0; v < 4; ++v) xp4[gt][v] = bias;
    }
    const f32x4* wr0 = (const f32x4*)(W_ih + (size_t)u * 64);
    const f32x4* wr1 = (const f32x4*)(W_ih + (size_t)(128 + u) * 64);
    const f32x4* wr2 = (const f32x4*)(W_ih + (size_t)(256 + u) * 64);
    const f32x4* wr3 = (const f32x4*)(W_ih + (size_t)(384 + u) * 64);
    for (int e4 = 0; e4 < 16; ++e4) {
      f32x4 w0 = wr0[e4], w1 = wr1[e4], w2 = wr2[e4], w3 = wr3[e4];
#pragma unroll
      for (int j = 0; j < 4; ++j) {
        int e = e4 * 4 + j;
        float we0 = W_enc[e * 3], we1 = W_enc[e * 3 + 1], we2 = W_enc[e * 3 + 2];
        float be = b_enc[e];
#pragma unroll
        for (int v = 0; v < 4; ++v) {
          float ev = fmaf(we0, xr0[v], fmaf(we1, xr1[v], fmaf(we2, xr2[v], be)));
          xp4[0][v] = fmaf(w0[j], ev, xp4[0][v]);
          xp4[1][v] = fmaf(w1[j], ev, xp4[1][v]);
          xp4[2][v] = fmaf(w2[j], ev, xp4[2][v]);
          xp4[3][v] = fmaf(w3[j], ev, xp4[3][v]);
        }
      }
    }
#pragma unroll
    for (int gt = 0; gt < 4; ++gt) {
      float s = (gt == 2) ? (-2.0f * K1) : (-K1);
#pragma unroll
      for (int v = 0; v < 4; ++v) xp4[gt][v] *= s;
      *(f32x4*)(lds + XP_BASE + gt * 8192 + (unsigned)tid * 16) = xp4[gt];
    }
  }

  // ---- W_hh bf16 B-fragments, prescaled into exp2 domain (R1-verified layout) ----
  short8 bw[4][4];
#pragma unroll
  for (int gt = 0; gt < 4; ++gt) {
    float s = (gt == 2) ? (-2.0f * K1) : (-K1);
#pragma unroll
    for (int kt = 0; kt < 4; ++kt) {
      const float* p = W_hh + (size_t)(gt * 128 + u) * HID + kt * 32 + 8 * l4;
      short8 f;
#pragma unroll
      for (int j = 0; j < 8; ++j) f[j] = (short)f2bf(s * p[j]);
      bw[gt][kt] = f;
    }
  }

  // c held in scaled domain as pairs: ctA={v0,v1}, ctB={v2,v3}
  f32x2 ctA = {0.0f, 0.0f}, ctB = {0.0f, 0.0f};

  // ---- LDS addresses (swizzle bits 4-6; kt=2,3 fold as +128: bit7, no carry) ----
  const unsigned swzA =
      (((unsigned)(l15 & 7)) << 4) ^ (((unsigned)(l15 & 8)) << 2);
  unsigned rd0 = ((unsigned)(l15 * 256 + l4 * 16)) ^ swzA;       // kt0, buf0
  unsigned rd1 = ((unsigned)(l15 * 256 + l4 * 16 + 64)) ^ swzA;  // kt1, buf0
  unsigned wr0, wr1, wr2, wr3;
  {
    unsigned rr = (unsigned)(4 * l4);
#define WRADDR(v) ((((rr + v) * 256 + (unsigned)u * 2) ^ (((rr + v) & 7u) << 4) ^ \
                    (((rr + v) & 8u) << 2)) + HB1)
    wr0 = WRADDR(0); wr1 = WRADDR(1); wr2 = WRADDR(2); wr3 = WRADDR(3);
#undef WRADDR
  }
  const unsigned xpA = (unsigned)tid * 16;
  const float wdu = W_dec[u];
  unsigned ptv = PART + (unsigned)(wav * WSTRIDE + 4 * l4) * 4;  // +=64/step
  const f32x2 onev = {1.0f, 1.0f};
  const f32x2 kposv = {2.0f * K1, 2.0f * K1};
  const f32x2 knegv = {-2.0f * K1, -2.0f * K1};
  const f32x2 wduv = {wdu, wdu};

  __syncthreads();

  // gate math in exp2 domain (R7-verified), on f32x2 pairs (plain vector ops):
  //   ct' = [ct*A*G + k(1-eg)*F]/(F*AG);  h = (1-ec)/(Bo*(1+ec))
  //   folds: F*AG = fma(ef,AG,AG); tt*F = fma(tt,ef,tt); Bo*E = fma(eo,E,E)
#define ACT2(S0, S1, S2, S3, CT, HOUT, PZOUT)                                  \
  {                                                                            \
    f32x2 ea, ef, eg, eo;                                                      \
    ea[0] = __builtin_amdgcn_exp2f(S0[0]);                                     \
    ea[1] = __builtin_amdgcn_exp2f(S0[1]);                                     \
    ef[0] = __builtin_amdgcn_exp2f(S1[0]);                                     \
    ef[1] = __builtin_amdgcn_exp2f(S1[1]);                                     \
    eg[0] = __builtin_amdgcn_exp2f(S2[0]);                                     \
    eg[1] = __builtin_amdgcn_exp2f(S2[1]);                                     \
    eo[0] = __builtin_amdgcn_exp2f(S3[0]);                                     \
    eo[1] = __builtin_amdgcn_exp2f(S3[1]);                                     \
    f32x2 A = ea + onev;                                                       \
    f32x2 G = eg + onev;                                                       \
    f32x2 AG = A * G;                                                          \
    f32x2 FAG = vfma(ef, AG, AG);                                              \
    f32x2 rv;                                                                  \
    rv[0] = __builtin_amdgcn_rcpf(FAG[0]);                                     \
    rv[1] = __builtin_amdgcn_rcpf(FAG[1]);                                     \
    f32x2 tt = vfma(eg, kposv, knegv);                                         \
    f32x2 ttF = vfma(tt, ef, tt);                                              \
    f32x2 num = vfma(CT, AG, ttF);                                             \
    f32x2 cn = num * rv;                                                       \
    CT = cn;                                                                   \
    f32x2 ec;                                                                  \
    ec[0] = __builtin_amdgcn_exp2f(cn[0]);                                     \
    ec[1] = __builtin_amdgcn_exp2f(cn[1]);                                     \
    f32x2 E = ec + onev;                                                       \
    f32x2 BoE = vfma(eo, E, E);                                                \
    f32x2 r2v;                                                                 \
    r2v[0] = __builtin_amdgcn_rcpf(BoE[0]);                                    \
    r2v[1] = __builtin_amdgcn_rcpf(BoE[1]);                                    \
    f32x2 mec = onev - ec;                                                     \
    HOUT = mec * r2v;                                                          \
    PZOUT = HOUT * wduv;                                                       \
  }

#pragma clang loop unroll(disable)
  for (int t = 0; t < T_STEPS; ++t) {
    f32x4 xpr0 = *(const f32x4*)(lds + XP_BASE + 0 * 8192 + xpA);
    f32x4 xpr1 = *(const f32x4*)(lds + XP_BASE + 1 * 8192 + xpA);
    f32x4 xpr2 = *(const f32x4*)(lds + XP_BASE + 2 * 8192 + xpA);
    f32x4 xpr3 = *(const f32x4*)(lds + XP_BASE + 3 * 8192 + xpA);
    short8 af0 = *(const short8*)(lds + rd0);
    short8 af1 = *(const short8*)(lds + rd1);
    short8 af2 = *(const short8*)(lds + rd0 + 128);
    short8 af3 = *(const short8*)(lds + rd1 + 128);
    f32x4 a0 = __builtin_amdgcn_mfma_f32_16x16x32_bf16(af0, bw[0][0], xpr0, 0, 0, 0);
    f32x4 a1 = __builtin_amdgcn_mfma_f32_16x16x32_bf16(af0, bw[1][0], xpr1, 0, 0, 0);
    f32x4 a2 = __builtin_amdgcn_mfma_f32_16x16x32_bf16(af0, bw[2][0], xpr2, 0, 0, 0);
    f32x4 a3 = __builtin_amdgcn_mfma_f32_16x16x32_bf16(af0, bw[3][0], xpr3, 0, 0, 0);
    a0 = __builtin_amdgcn_mfma_f32_16x16x32_bf16(af1, bw[0][1], a0, 0, 0, 0);
    a1 = __builtin_amdgcn_mfma_f32_16x16x32_bf16(af1, bw[1][1], a1, 0, 0, 0);
    a2 = __builtin_amdgcn_mfma_f32_16x16x32_bf16(af1, bw[2][1], a2, 0, 0, 0);
    a3 = __builtin_amdgcn_mfma_f32_16x16x32_bf16(af1, bw[3][1], a3, 0, 0, 0);
    a0 = __builtin_amdgcn_mfma_f32_16x16x32_bf16(af2, bw[0][2], a0, 0, 0, 0);
    a1 = __builtin_amdgcn_mfma_f32_16x16x32_bf16(af2, bw[1][2], a1, 0, 0, 0);
    a2 = __builtin_amdgcn_mfma_f32_16x16x32_bf16(af2, bw[2][2], a2, 0, 0, 0);
    a3 = __builtin_amdgcn_mfma_f32_16x16x32_bf16(af2, bw[3][2], a3, 0, 0, 0);
    a0 = __builtin_amdgcn_mfma_f32_16x16x32_bf16(af3, bw[0][3], a0, 0, 0, 0);
    a1 = __builtin_amdgcn_mfma_f32_16x16x32_bf16(af3, bw[1][3], a1, 0, 0, 0);
    a2 = __builtin_amdgcn_mfma_f32_16x16x32_bf16(af3, bw[2][3], a2, 0, 0, 0);
    a3 = __builtin_amdgcn_mfma_f32_16x16x32_bf16(af3, bw[3][3], a3, 0, 0, 0);

    // packed ACT: pair {v0,v1} then {v2,v3}
    f32x2 s0, s1, s2, s3, hA, hB, pzA, pzB;
    s0[0] = a0[0]; s0[1] = a0[1];
    s1[0] = a1[0]; s1[1] = a1[1];
    s2[0] = a2[0]; s2[1] = a2[1];
    s3[0] = a3[0]; s3[1] = a3[1];
    ACT2(s0, s1, s2, s3, ctA, hA, pzA)
    s0[0] = a0[2]; s0[1] = a0[3];
    s1[0] = a1[2]; s1[1] = a1[3];
    s2[0] = a2[2]; s2[1] = a2[3];
    s3[0] = a3[2]; s3[1] = a3[3];
    ACT2(s0, s1, s2, s3, ctB, hB, pzB)

    // pack h pairs with v_cvt_pk_bf16_f32 (RTNE, == f2bf rounding; R14-proven)
    unsigned r01, r23;
    asm("v_cvt_pk_bf16_f32 %0, %1, %2" : "=v"(r01) : "v"(hA[0]), "v"(hA[1]));
    asm("v_cvt_pk_bf16_f32 %0, %1, %2" : "=v"(r23) : "v"(hB[0]), "v"(hB[1]));
    *(unsigned short*)(lds + wr0) = (unsigned short)r01;
    *(unsigned short*)(lds + wr1) = (unsigned short)(r01 >> 16);
    *(unsigned short*)(lds + wr2) = (unsigned short)r23;
    *(unsigned short*)(lds + wr3) = (unsigned short)(r23 >> 16);
    // in-register 16-lane (l15) butterfly via DPP; l4 rows preserved
    f32x4 pz;
    pz[0] = pzA[0]; pz[1] = pzA[1]; pz[2] = pzB[0]; pz[3] = pzB[1];
#pragma unroll
    for (int v = 0; v < 4; ++v)
      pz[v] = dppadd<0x140>(dppadd<0x141>(dppadd<0x4E>(dppadd<0xB1>(pz[v]))));
    if (l15 == 0) *(f32x4*)(lds + ptv) = pz;
    __syncthreads();
    rd0 ^= 4096; rd1 ^= 4096;
    wr0 ^= 4096; wr1 ^= 4096; wr2 ^= 4096; wr3 ^= 4096;
    ptv += 64;
  }
#undef ACT2

  // ---- epilogue: cross-wave sum of partials + sigmoid + coalesced store ----
  const float bdec = b_dec[0];
  const float* partf = (const float*)(lds + PART);
  for (int i = tid; i < 16 * T_STEPS; i += 512) {
    int r = i / T_STEPS, t = i - r * T_STEPS;
    float s = 0.0f;
#pragma unroll
    for (int w = 0; w < 8; ++w) s += partf[w * WSTRIDE + t * 16 + r];
    out[(size_t)(row0 + r) * T_STEPS + t] = sigm(s + bdec);
  }
}

extern "C" void kernel_launch(void* const* d_in, const int* in_sizes, int n_in,
                              void* d_out, int out_size, void* d_ws, size_t ws_size,
                              hipStream_t stream) {
  const float* x = (const float*)d_in[0];
  const float* W_enc = (const float*)d_in[1];
  const float* b_enc = (const float*)d_in[2];
  const float* W_ih = (const float*)d_in[3];
  const float* W_hh = (const float*)d_in[4];
  const float* b_ih = (const float*)d_in[5];
  const float* b_hh = (const float*)d_in[6];
  const float* W_dec = (const float*)d_in[7];
  const float* b_dec = (const float*)d_in[8];
  float* out = (float*)d_out;

  dim3 grid(NBLK);  // 1024 blocks x 16 rows
  dim3 block(512);
  lstm_fused<<<grid, block, 0, stream>>>(x, W_enc, b_enc, W_ih, W_hh, b_ih, b_hh,
                                         W_dec, b_dec, out);
}